// Round 6
// baseline (240.950 us; speedup 1.0000x reference)
//
#include <hip/hip_runtime.h>
#include <math.h>

// BucketingBBoxCoder decode: B*N = 1,048,576 proposals.
// Per proposal: 28 f32 cls logits (4 sides x 7 buckets), 28 f32 offsets,
// 4 f32 proposal box -> 4 f32 bbox + 1 f32 conf.
//
// R1-R4: ~98us invariant, no CU counter saturated. Diagnosis: IC port
// saturated ~2.7 TB/s (read-once stream allocating into L3: fill+read).
// R5: NT cls/off loads -> kernel fell below harness memsets; 262->244.
// R6: NT everything -> 239.2. Kernel now a pure HBM stream, ~65-75us vs
// 40-43us byte floor (273 MB at 6.3-6.9 TB/s; fills calibrate 6.9).
// Residual theory: latency-hiding capacity — occupancy stuck ~44% in all
// measured rounds; wave lifetime = 15 VMEM + 2 LDS round-trips + ~400 VALU.
// R7 (this): block 64->128 (2 waves), LDS 14,848 B -> cap 20 waves/CU
// (62.5%), half the workgroups. Pure A/B on block size.
// Predict: harness ~225-232 if wave-limited; unchanged => stream ceiling,
// declare roofline.

#define TILE 128    // proposals per block == threads per block (2 waves)
#define PAD_ROW 29  // 28 floats + 1 pad; odd stride -> conflict-free on 32 banks

typedef float f32x4_v __attribute__((ext_vector_type(4)));

__global__ __launch_bounds__(128) void bucketing_bbox_wave_kernel(
    const float* __restrict__ proposals,
    const float* __restrict__ cls_preds,
    const float* __restrict__ offset_preds,
    float* __restrict__ out_bboxes,
    float* __restrict__ out_conf)
{
    __shared__ float lds[TILE * PAD_ROW];  // 14,848 B -> 10 blocks/CU

    const int t = threadIdx.x;
    const size_t base = (size_t)blockIdx.x * TILE;   // first proposal of tile
    const size_t gid = base + t;

    // ---- Coalesced global loads: 7 float4/thread/array, lane-contiguous ----
    // ALL loads non-temporal: every input byte is consumed exactly once per
    // dispatch; allocating in L2/L3 saturates the IC port (the R1-R4 wall).
    const f32x4_v* clsv = reinterpret_cast<const f32x4_v*>(cls_preds) + base * 7;
    const f32x4_v* offv = reinterpret_cast<const f32x4_v*>(offset_preds) + base * 7;
    f32x4_v creg[7], oreg[7];
#pragma unroll
    for (int k = 0; k < 7; ++k) creg[k] = __builtin_nontemporal_load(clsv + t + TILE * k);
#pragma unroll
    for (int k = 0; k < 7; ++k) oreg[k] = __builtin_nontemporal_load(offv + t + TILE * k);
    f32x4_v prv = __builtin_nontemporal_load(
        reinterpret_cast<const f32x4_v*>(proposals) + gid);

    // float4 index owned at iter k is f = t + 128k; proposal p = f/7, e = f%7.
    // Incremental: f += 128 => p += 18, e += 2 (128 = 18*7 + 2), wrap at 7.
    const int p0 = t / 7;
    const int e0 = t - p0 * 7;

    // ---- Phase 1: cls through LDS ----
    {
        int p = p0, e = e0;
#pragma unroll
        for (int k = 0; k < 7; ++k) {
            int a = p * PAD_ROW + 4 * e;
            lds[a + 0] = creg[k][0];
            lds[a + 1] = creg[k][1];
            lds[a + 2] = creg[k][2];
            lds[a + 3] = creg[k][3];
            p += 18; e += 2;
            if (e >= 7) { e -= 7; p += 1; }
        }
    }
    __syncthreads();

    float cls[28];
    const int rb = t * PAD_ROW;
#pragma unroll
    for (int j = 0; j < 28; ++j) cls[j] = lds[rb + j];  // stride 29: conflict-free
    __syncthreads();  // cls reads done; buffer free

    // ---- Phase 2 writes FIRST so they overlap the compute below ----
    {
        int p = p0, e = e0;
#pragma unroll
        for (int k = 0; k < 7; ++k) {
            int a = p * PAD_ROW + 4 * e;
            lds[a + 0] = oreg[k][0];
            lds[a + 1] = oreg[k][1];
            lds[a + 2] = oreg[k][2];
            lds[a + 3] = oreg[k][3];
            p += 18; e += 2;
            if (e >= 7) { e -= 7; p += 1; }
        }
    }

    // ---- top-2 per side + softmax probs + confidence (no LDS dependency) ----
    int   lab0s[4];
    float conf_sum = 0.0f;
#pragma unroll
    for (int s = 0; s < 4; ++s) {
        float best0 = cls[s * 7 + 0];
        float best1 = -INFINITY;
        int   lab0 = 0, lab1 = 0;
#pragma unroll
        for (int j = 1; j < 7; ++j) {
            float x = cls[s * 7 + j];
            bool gt0 = x > best0;
            bool gt1 = x > best1;
            // strict > with ascending j => lowest index wins ties (lax.top_k)
            best1 = gt0 ? best0 : (gt1 ? x : best1);
            lab1  = gt0 ? lab0  : (gt1 ? j : lab1);
            best0 = gt0 ? x : best0;
            lab0  = gt0 ? j : lab0;
        }
        float sum = 0.0f;
#pragma unroll
        for (int j = 0; j < 7; ++j) sum += __expf(cls[s * 7 + j] - best0);
        float inv = 1.0f / sum;
        float p0s = inv;
        float p1s = __expf(best1 - best0) * inv;

        lab0s[s] = lab0;
        float neighbor = fabsf((float)(lab0 - lab1)) - 1.0f;
        conf_sum += p0s + p1s * neighbor;
    }

    // ---- Proposal geometry (still no LDS dependency) ----
    float cx = (prv[0] + prv[2]) * 0.5f;
    float cy = (prv[1] + prv[3]) * 0.5f;
    float pw = (prv[2] - prv[0]) * 3.0f;
    float ph = (prv[3] - prv[1]) * 3.0f;
    float px1 = cx - 0.5f * pw;
    float px2 = cx + 0.5f * pw;
    float py1 = cy - 0.5f * ph;
    float py2 = cy + 0.5f * ph;
    float bw = pw / 14.0f;
    float bh = ph / 14.0f;

    __syncthreads();  // offsets staged

    float osel0 = lds[rb + 0  + lab0s[0]];
    float osel1 = lds[rb + 7  + lab0s[1]];
    float osel2 = lds[rb + 14 + lab0s[2]];
    float osel3 = lds[rb + 21 + lab0s[3]];

    float l_b = px1 + (0.5f + (float)lab0s[0]) * bw;
    float r_b = px2 - (0.5f + (float)lab0s[1]) * bw;
    float t_b = py1 + (0.5f + (float)lab0s[2]) * bh;
    float d_b = py2 - (0.5f + (float)lab0s[3]) * bh;

    float x1 = l_b - osel0 * bw;
    float x2 = r_b - osel1 * bw;
    float y1 = t_b - osel2 * bh;
    float y2 = d_b - osel3 * bh;

    const float Wm = 1332.0f;  // W - 1
    const float Hm = 799.0f;   // H - 1
    x1 = fminf(fmaxf(x1, 0.0f), Wm);
    x2 = fminf(fmaxf(x2, 0.0f), Wm);
    y1 = fminf(fmaxf(y1, 0.0f), Hm);
    y2 = fminf(fmaxf(y2, 0.0f), Hm);

    // Non-temporal stores: outputs are never re-read by this kernel.
    f32x4_v bb = {x1, y1, x2, y2};
    __builtin_nontemporal_store(bb, reinterpret_cast<f32x4_v*>(out_bboxes) + gid);
    __builtin_nontemporal_store(conf_sum * 0.25f, out_conf + gid);
}

// Tail fallback (per-thread strided; only used if total % TILE != 0 — it isn't
// for this problem's shape, but keep it correct for any size).
__global__ __launch_bounds__(256) void bucketing_bbox_tail_kernel(
    const float* __restrict__ proposals,
    const float* __restrict__ cls_preds,
    const float* __restrict__ offset_preds,
    float* __restrict__ out_bboxes,
    float* __restrict__ out_conf,
    int start, int total)
{
    int i = start + blockIdx.x * blockDim.x + threadIdx.x;
    if (i >= total) return;

    float4 pr = reinterpret_cast<const float4*>(proposals)[i];
    float cls[28], offs[28];
    {
        const float4* cp = reinterpret_cast<const float4*>(cls_preds + (size_t)i * 28);
        const float4* op = reinterpret_cast<const float4*>(offset_preds + (size_t)i * 28);
#pragma unroll
        for (int k = 0; k < 7; ++k) reinterpret_cast<float4*>(cls)[k] = cp[k];
#pragma unroll
        for (int k = 0; k < 7; ++k) reinterpret_cast<float4*>(offs)[k] = op[k];
    }
    float cx = (pr.x + pr.z) * 0.5f;
    float cy = (pr.y + pr.w) * 0.5f;
    float pw = (pr.z - pr.x) * 3.0f;
    float ph = (pr.w - pr.y) * 3.0f;
    float px1 = cx - 0.5f * pw, px2 = cx + 0.5f * pw;
    float py1 = cy - 0.5f * ph, py2 = cy + 0.5f * ph;
    float bw = pw / 14.0f, bh = ph / 14.0f;

    int lab0s[4]; float offsel[4]; float conf_sum = 0.0f;
#pragma unroll
    for (int s = 0; s < 4; ++s) {
        float best0 = cls[s * 7], best1 = -INFINITY;
        int lab0 = 0, lab1 = 0;
        float osel = offs[s * 7];
#pragma unroll
        for (int j = 1; j < 7; ++j) {
            float x = cls[s * 7 + j], o = offs[s * 7 + j];
            bool gt0 = x > best0, gt1 = x > best1;
            best1 = gt0 ? best0 : (gt1 ? x : best1);
            lab1  = gt0 ? lab0  : (gt1 ? j : lab1);
            best0 = gt0 ? x : best0;
            lab0  = gt0 ? j : lab0;
            osel  = gt0 ? o : osel;
        }
        float sum = 0.0f;
#pragma unroll
        for (int j = 0; j < 7; ++j) sum += __expf(cls[s * 7 + j] - best0);
        float inv = 1.0f / sum;
        lab0s[s] = lab0; offsel[s] = osel;
        conf_sum += inv + __expf(best1 - best0) * inv * (fabsf((float)(lab0 - lab1)) - 1.0f);
    }
    float x1 = px1 + (0.5f + (float)lab0s[0]) * bw - offsel[0] * bw;
    float x2 = px2 - (0.5f + (float)lab0s[1]) * bw - offsel[1] * bw;
    float y1 = py1 + (0.5f + (float)lab0s[2]) * bh - offsel[2] * bh;
    float y2 = py2 - (0.5f + (float)lab0s[3]) * bh - offsel[3] * bh;
    x1 = fminf(fmaxf(x1, 0.0f), 1332.0f);
    x2 = fminf(fmaxf(x2, 0.0f), 1332.0f);
    y1 = fminf(fmaxf(y1, 0.0f), 799.0f);
    y2 = fminf(fmaxf(y2, 0.0f), 799.0f);
    reinterpret_cast<float4*>(out_bboxes)[i] = make_float4(x1, y1, x2, y2);
    out_conf[i] = conf_sum * 0.25f;
}

extern "C" void kernel_launch(void* const* d_in, const int* in_sizes, int n_in,
                              void* d_out, int out_size, void* d_ws, size_t ws_size,
                              hipStream_t stream) {
    const float* proposals    = (const float*)d_in[0];
    const float* cls_preds    = (const float*)d_in[1];
    const float* offset_preds = (const float*)d_in[2];

    int total = in_sizes[0] / 4;  // B*N proposals (1,048,576)

    float* out_bboxes = (float*)d_out;                       // total*4
    float* out_conf   = (float*)d_out + (size_t)total * 4;   // total

    int full_tiles = total / TILE;   // 8,192 for this shape
    int rem = total - full_tiles * TILE;

    if (full_tiles > 0) {
        bucketing_bbox_wave_kernel<<<full_tiles, TILE, 0, stream>>>(
            proposals, cls_preds, offset_preds, out_bboxes, out_conf);
    }
    if (rem > 0) {
        int start = full_tiles * TILE;
        bucketing_bbox_tail_kernel<<<(rem + 255) / 256, 256, 0, stream>>>(
            proposals, cls_preds, offset_preds, out_bboxes, out_conf, start, total);
    }
}